// Round 5
// baseline (27089.960 us; speedup 1.0000x reference)
//
#include <hip/hip_runtime.h>

// RNN-VAE on MI355X. 16 WGs x 16 batch rows, 8 waves/WG, waves_per_eu(2,2).
// R5: weight streaming moved off the register file entirely:
// per step, non-pinned weight slices flow through a 2-slot x 64KB LDS ring
// filled with __builtin_amdgcn_global_load_lds (16B, zero staging VGPRs),
// one-phase prefetch distance, barrier-paced. 3 t-invariant slices are
// reg-pinned (96 VGPR) under a forced 256-VGPR budget (amdgpu_waves_per_eu).
// Gate-aligned wave mapping from R4: in-register c/h update, h exchanged
// via small LDS double-buffer, fused out-proj in dec.

typedef __bf16 bf16x8 __attribute__((ext_vector_type(8)));
typedef float f32x4 __attribute__((ext_vector_type(4)));
typedef unsigned int uint4v __attribute__((ext_vector_type(4)));

#define DI __device__ __forceinline__
#define WPEU __attribute__((amdgpu_waves_per_eu(2, 2)))

DI unsigned short f2bf(float f) {            // fp32 -> bf16 RNE
  unsigned int u = __float_as_uint(f);
  u += 0x7fffu + ((u >> 16) & 1u);
  return (unsigned short)(u >> 16);
}
DI float sigf(float v) { return 1.0f / (1.0f + __expf(-v)); }

union FragU { bf16x8 v; unsigned short us[8]; };

DI f32x4 mfma16(bf16x8 a, bf16x8 b, f32x4 c) {
  // D[row=(lane>>4)*4+q][col=lane&15]; A[row=lane&15][k=(lane>>4)*8+j]
  return __builtin_amdgcn_mfma_f32_16x16x32_bf16(a, b, c, 0, 0, 0);
}

DI void glds16(const void* g, void* l) {     // global -> LDS, 16B x 64 lanes
  __builtin_amdgcn_global_load_lds(
      (const __attribute__((address_space(1))) unsigned int*)g,
      (__attribute__((address_space(3))) unsigned int*)l, 16, 0, 0);
}

// ---- weight fragment packing: src (K x N fp32, row-major) ->
// frag[j] = src[kt*32+(lane>>4)*8+j][nt*16+(lane&15)], flat idx (kt*NT+nt)*64+lane
__global__ void pack_frags(const float* __restrict__ src,
                           unsigned short* __restrict__ dst, int K, int N) {
  int KT = K >> 5, NT = N >> 4;
  int total = KT * NT * 64;
  for (int idx = blockIdx.x * blockDim.x + threadIdx.x; idx < total;
       idx += gridDim.x * blockDim.x) {
    int lane = idx & 63;
    int fi = idx >> 6;
    int nt = fi % NT;
    int kt = fi / NT;
    int r0 = kt * 32 + (lane >> 4) * 8;
    int col = nt * 16 + (lane & 15);
    unsigned int w[4];
#pragma unroll
    for (int p = 0; p < 4; ++p) {
      unsigned int lo = f2bf(src[(size_t)(r0 + 2 * p) * N + col]);
      unsigned int hi = f2bf(src[(size_t)(r0 + 2 * p + 1) * N + col]);
      w[p] = lo | (hi << 16);
    }
    *(uint4v*)(dst + (size_t)idx * 8) = (uint4v){w[0], w[1], w[2], w[3]};
  }
}

// ---- per-(b,t) nonzero mask: flags[b>>4][t] bit (b&15) ----
__global__ void mask_flags(const float* __restrict__ x,
                           unsigned int* __restrict__ flags) {
  const int t = blockIdx.x;          // 1024
  const int b = threadIdx.x;         // 256
  const float* p = x + ((size_t)b * 1024 + t) * 128;
  bool nz = false;
#pragma unroll 8
  for (int k = 0; k < 32; ++k) {
    float4 v = *(const float4*)(p + k * 4);
    nz = nz || v.x != 0.f || v.y != 0.f || v.z != 0.f || v.w != 0.f;
  }
  unsigned long long bal = __ballot((int)nz);
  if ((threadIdx.x & 15) == 0)
    flags[(size_t)(b >> 4) * 1024 + t] =
        (unsigned int)((bal >> (threadIdx.x & 48)) & 0xFFFFull);
}

// STAGE: issue one 64KB slice (64 nt-rows x 1KB) into LDS ring slot.
// wave w covers nt = r*8+w; LDS dest is wave-uniform base (HW adds lane*16B).
#define STAGE(GSLICE, LBASE) do { _Pragma("unroll")                        \
    for (int r = 0; r < 8; ++r) {                                          \
      const int nt_ = r * 8 + w;                                           \
      glds16((const void*)((GSLICE) + (size_t)(nt_ * 64 + lane) * 8),      \
             (void*)((LBASE) + nt_ * 512));                                \
    } } while (0)

// CONSUME: 8 frag reads from ring slot + 8 MFMAs with A-operand AOP.
#define CONSUME(AOP, LBASE) do { _Pragma("unroll")                         \
    for (int f = 0; f < 8; ++f) {                                          \
      bf16x8 b_ = *(const bf16x8*)&(LBASE)[ntf[f] * 512 + lane * 8];       \
      acc[f] = mfma16((AOP), b_, acc[f]); } } while (0)

#define PIN_MFMA(AOP, PIN) do { _Pragma("unroll")                          \
    for (int f = 0; f < 8; ++f) acc[f] = mfma16((AOP), (PIN)[f], acc[f]);  \
  } while (0)

// =========================== encoder ======================================
// pinned: W kt0,1 + U kt0 (regs). streamed S0..S8 = {Wk2,Wk3,Uk1..Uk7}.
__global__ __launch_bounds__(512) WPEU
void enc_rnn(const float* __restrict__ x,              // [256][1024][128]
             const unsigned short* __restrict__ Wef,   // 128x1024 frags
             const unsigned short* __restrict__ Uef,   // 256x1024 frags
             const float* __restrict__ benc,
             const unsigned int* __restrict__ flags,   // [16][1024]
             unsigned short* __restrict__ hfin) {
  __shared__ __align__(16) unsigned short ring[2 * 64 * 512];     // 128KB
  __shared__ __align__(16) unsigned short hfrag[2 * 8 * 64 * 8];  // 16KB

  const int tid = threadIdx.x;
  const int w = tid >> 6, lane = tid & 63;
  const int l15 = lane & 15, lkg = lane >> 4;
  const int wg = blockIdx.x, b0 = wg * 16;
  int ntf[8];
#pragma unroll
  for (int f = 0; f < 8; ++f) ntf[f] = (f >> 1) * 16 + 2 * w + (f & 1);

  ((uint4v*)hfrag)[tid] = (uint4v){0u, 0u, 0u, 0u};
  ((uint4v*)hfrag)[tid + 512] = (uint4v){0u, 0u, 0u, 0u};

  const bf16x8* Wl = (const bf16x8*)Wef + lane;
  const bf16x8* Ul = (const bf16x8*)Uef + lane;
  const unsigned int* flagp = flags + (size_t)wg * 1024;

  bf16x8 wp0[8], wp1[8], up0[8];           // reg pins: W kt0,1 + U kt0
#pragma unroll
  for (int f = 0; f < 8; ++f) {
    wp0[f] = Wl[(0 * 64 + ntf[f]) * 64];
    wp1[f] = Wl[(1 * 64 + ntf[f]) * 64];
    up0[f] = Ul[(0 * 64 + ntf[f]) * 64];
  }

  float bfr[8];
#pragma unroll
  for (int f = 0; f < 8; ++f) bfr[f] = benc[ntf[f] * 16 + l15];

  float c8[8];
  unsigned short hreg[8];
#pragma unroll
  for (int i = 0; i < 8; ++i) { c8[i] = 0.f; hreg[i] = 0; }

  const float* xbase = x + (size_t)(b0 + l15) * 1024 * 128 + lkg * 8;
  const unsigned short* Wk2g = Wef + 2 * 32768;
  const unsigned short* Wk3g = Wef + 3 * 32768;

  bf16x8 hfr[8];
  int hb = 0, rp = 0;

  STAGE(Wk2g, ring);                       // prime S0 -> slot 0
  __syncthreads();

  for (int t = 0; t < 1024; ++t) {
    const unsigned int flag = flagp[t];
    if (flag == 0u) continue;              // uniform: carry h,c; ring keeps S0

    const float* xp = xbase + (size_t)t * 128;
    FragU xf[4];
#pragma unroll
    for (int kt = 0; kt < 4; ++kt) {
      float4 a = *(const float4*)(xp + kt * 32);
      float4 b = *(const float4*)(xp + kt * 32 + 4);
      xf[kt].us[0] = f2bf(a.x); xf[kt].us[1] = f2bf(a.y);
      xf[kt].us[2] = f2bf(a.z); xf[kt].us[3] = f2bf(a.w);
      xf[kt].us[4] = f2bf(b.x); xf[kt].us[5] = f2bf(b.y);
      xf[kt].us[6] = f2bf(b.z); xf[kt].us[7] = f2bf(b.w);
    }

    const unsigned short* hrd = hfrag + hb * 4096;
#pragma unroll
    for (int k = 0; k < 8; ++k) hfr[k] = *(const bf16x8*)&hrd[(k * 64 + lane) * 8];

    f32x4 acc[8];
#pragma unroll
    for (int f = 0; f < 8; ++f) acc[f] = (f32x4){bfr[f], bfr[f], bfr[f], bfr[f]};

    PIN_MFMA(xf[0].v, wp0);
    PIN_MFMA(xf[1].v, wp1);
    PIN_MFMA(hfr[0], up0);

    unsigned short* consA = ring + rp * 32768;
    unsigned short* consB = ring + (rp ^ 1) * 32768;

    STAGE(Wk3g,              consB); CONSUME(xf[2].v, consA); __syncthreads();
    STAGE(Uef + 1 * 32768,   consA); CONSUME(xf[3].v, consB); __syncthreads();
    STAGE(Uef + 2 * 32768,   consB); CONSUME(hfr[1],  consA); __syncthreads();
    STAGE(Uef + 3 * 32768,   consA); CONSUME(hfr[2],  consB); __syncthreads();
    STAGE(Uef + 4 * 32768,   consB); CONSUME(hfr[3],  consA); __syncthreads();
    STAGE(Uef + 5 * 32768,   consA); CONSUME(hfr[4],  consB); __syncthreads();
    STAGE(Uef + 6 * 32768,   consB); CONSUME(hfr[5],  consA); __syncthreads();
    STAGE(Uef + 7 * 32768,   consA); CONSUME(hfr[6],  consB); __syncthreads();
    STAGE(Wk2g,              consB); CONSUME(hfr[7],  consA); __syncthreads();
    rp ^= 1;

    // in-register gate fusion + h broadcast (masked rows carry h,c)
    unsigned short* hwr = hfrag + (hb ^ 1) * 4096;
#pragma unroll
    for (int p = 0; p < 2; ++p) {
#pragma unroll
      for (int q = 0; q < 4; ++q) {
        float iv = sigf(acc[0 * 2 + p][q]);
        float fv = sigf(acc[1 * 2 + p][q]);
        float gv = fmaxf(acc[2 * 2 + p][q], 0.f);
        float ov = sigf(acc[3 * 2 + p][q]);
        float cn = fv * c8[p * 4 + q] + iv * gv;
        float hn = ov * fmaxf(cn, 0.f);
        bool m = (flag >> (lkg * 4 + q)) & 1u;
        c8[p * 4 + q] = m ? cn : c8[p * 4 + q];
        unsigned short hh = m ? f2bf(hn) : hreg[p * 4 + q];
        hreg[p * 4 + q] = hh;
        hwr[((w * 64 + (p * 2 + (l15 >> 3)) * 16 + lkg * 4 + q)) * 8 + (l15 & 7)] = hh;
      }
    }
    __syncthreads();
    hb ^= 1;
  }

  ((uint4v*)hfin)[(size_t)wg * 512 + tid] =
      ((const uint4v*)(hfrag + hb * 4096))[tid];
}

// =========================== decoder ======================================
// pinned: W_dec[:64] kt0,1 + U kt0 (regs). streamed S0..S6 = {Uk1..Uk7}.
__global__ __launch_bounds__(512) WPEU
void dec_rnn(const float* __restrict__ x,
             const unsigned short* __restrict__ Wd0f,   // 64x1024 frags
             const unsigned short* __restrict__ WdLf,   // 256x1024 frags
             const unsigned short* __restrict__ Udf,    // 256x1024 frags
             const float* __restrict__ bdec,
             const unsigned short* __restrict__ Wof,    // 256x64 frags
             const float* __restrict__ bout,
             const unsigned short* __restrict__ hfin,
             float* __restrict__ out) {
  __shared__ __align__(16) unsigned short ring[2 * 64 * 512];     // 128KB
  __shared__ __align__(16) unsigned short hfrag[2 * 8 * 64 * 8];  // 16KB
  __shared__ __align__(16) unsigned short woutlds[12 * 64 * 8];   // 12KB

  const int tid = threadIdx.x;
  const int w = tid >> 6, lane = tid & 63;
  const int l15 = lane & 15, lkg = lane >> 4;
  const int wg = blockIdx.x, b0 = wg * 16;
  int ntf[8];
#pragma unroll
  for (int f = 0; f < 8; ++f) ntf[f] = (f >> 1) * 16 + 2 * w + (f & 1);

  ((uint4v*)hfrag)[tid] = (uint4v){0u, 0u, 0u, 0u};
  ((uint4v*)hfrag)[tid + 512] = (uint4v){0u, 0u, 0u, 0u};
  ((uint4v*)woutlds)[tid] = ((const uint4v*)Wof)[tid];       // 768 uint4v total
  if (tid < 256)
    ((uint4v*)woutlds)[512 + tid] = ((const uint4v*)Wof)[512 + tid];

  const bf16x8* W0l = (const bf16x8*)Wd0f + lane;
  const bf16x8* WLl = (const bf16x8*)WdLf + lane;
  const bf16x8* Ul  = (const bf16x8*)Udf + lane;

  bf16x8 w0p0[8], w0p1[8], up0[8];          // reg pins
#pragma unroll
  for (int f = 0; f < 8; ++f) {
    w0p0[f] = W0l[(0 * 64 + ntf[f]) * 64];
    w0p1[f] = W0l[(1 * 64 + ntf[f]) * 64];
    up0[f]  = Ul[(0 * 64 + ntf[f]) * 64];
  }

  // lat = b_dec + h_fin @ W_dec[64:], packed to bf16 pairs
  uint2 latw[8];
  {
    f32x4 lat[8];
#pragma unroll
    for (int f = 0; f < 8; ++f) {
      float bd = bdec[ntf[f] * 16 + l15];
      lat[f] = (f32x4){bd, bd, bd, bd};
    }
#pragma unroll
    for (int kt = 0; kt < 8; ++kt) {
      bf16x8 hv = *(const bf16x8*)(hfin + (size_t)wg * 4096 +
                                   (size_t)(kt * 64 + lane) * 8);
#pragma unroll
      for (int f = 0; f < 8; ++f)
        lat[f] = mfma16(hv, WLl[(kt * 64 + ntf[f]) * 64], lat[f]);
    }
#pragma unroll
    for (int f = 0; f < 8; ++f) {
      latw[f].x = (unsigned int)f2bf(lat[f][0]) | ((unsigned int)f2bf(lat[f][1]) << 16);
      latw[f].y = (unsigned int)f2bf(lat[f][2]) | ((unsigned int)f2bf(lat[f][3]) << 16);
    }
  }

  bf16x8 wop[5];                            // Wout kt3..7 for out-waves
  if (w < 4) {
#pragma unroll
    for (int k = 0; k < 5; ++k)
      wop[k] = ((const bf16x8*)Wof)[((k + 3) * 4 + w) * 64 + lane];
  }
  const float bo = bout[(w & 3) * 16 + l15];

  float c8[8];
#pragma unroll
  for (int i = 0; i < 8; ++i) c8[i] = 0.f;

  const float* xbase = x + (size_t)(b0 + l15) * 1024 * 128 + lkg * 8;

  bf16x8 hfr[8];
  float4 xa[2][2];
  xa[0][0] = *(const float4*)(xbase);      xa[0][1] = *(const float4*)(xbase + 4);
  xa[1][0] = *(const float4*)(xbase + 32); xa[1][1] = *(const float4*)(xbase + 36);
  int hb = 0, rp = 0;

  STAGE(Udf + 1 * 32768, ring);            // prime S0=Uk1 -> slot 0
  __syncthreads();

  for (int t = 0; t < 1024; ++t) {
    FragU xf[2];
#pragma unroll
    for (int kt = 0; kt < 2; ++kt) {
      xf[kt].us[0] = f2bf(xa[kt][0].x); xf[kt].us[1] = f2bf(xa[kt][0].y);
      xf[kt].us[2] = f2bf(xa[kt][0].z); xf[kt].us[3] = f2bf(xa[kt][0].w);
      xf[kt].us[4] = f2bf(xa[kt][1].x); xf[kt].us[5] = f2bf(xa[kt][1].y);
      xf[kt].us[6] = f2bf(xa[kt][1].z); xf[kt].us[7] = f2bf(xa[kt][1].w);
    }

    const unsigned short* hrd = hfrag + hb * 4096;
#pragma unroll
    for (int k = 0; k < 8; ++k) hfr[k] = *(const bf16x8*)&hrd[(k * 64 + lane) * 8];

    f32x4 acc[8];
#pragma unroll
    for (int f = 0; f < 8; ++f)
      acc[f] = (f32x4){__uint_as_float(latw[f].x << 16),
                       __uint_as_float(latw[f].x & 0xFFFF0000u),
                       __uint_as_float(latw[f].y << 16),
                       __uint_as_float(latw[f].y & 0xFFFF0000u)};

    PIN_MFMA(xf[0].v, w0p0);
    PIN_MFMA(xf[1].v, w0p1);
    PIN_MFMA(hfr[0], up0);

    unsigned short* consA = ring + rp * 32768;
    unsigned short* consB = ring + (rp ^ 1) * 32768;

    STAGE(Udf + 2 * 32768, consB); CONSUME(hfr[1], consA); __syncthreads();
    STAGE(Udf + 3 * 32768, consA); CONSUME(hfr[2], consB); __syncthreads();
    STAGE(Udf + 4 * 32768, consB); CONSUME(hfr[3], consA); __syncthreads();
    STAGE(Udf + 5 * 32768, consA); CONSUME(hfr[4], consB); __syncthreads();
    STAGE(Udf + 6 * 32768, consB); CONSUME(hfr[5], consA); __syncthreads();
    STAGE(Udf + 7 * 32768, consA); CONSUME(hfr[6], consB); __syncthreads();
    STAGE(Udf + 1 * 32768, consB); CONSUME(hfr[7], consA); __syncthreads();
    rp ^= 1;

    if (t < 1023) {             // prefetch x for t+1 (covered by gate phase)
      const float* xq = xbase + (size_t)(t + 1) * 128;
      xa[0][0] = *(const float4*)(xq);      xa[0][1] = *(const float4*)(xq + 4);
      xa[1][0] = *(const float4*)(xq + 32); xa[1][1] = *(const float4*)(xq + 36);
    }

    unsigned short* hwr = hfrag + (hb ^ 1) * 4096;
#pragma unroll
    for (int p = 0; p < 2; ++p) {
#pragma unroll
      for (int q = 0; q < 4; ++q) {
        float iv = sigf(acc[0 * 2 + p][q]);
        float fv = sigf(acc[1 * 2 + p][q]);
        float gv = fmaxf(acc[2 * 2 + p][q], 0.f);
        float ov = sigf(acc[3 * 2 + p][q]);
        float cn = fv * c8[p * 4 + q] + iv * gv;
        float hn = ov * fmaxf(cn, 0.f);
        c8[p * 4 + q] = cn;
        hwr[((w * 64 + (p * 2 + (l15 >> 3)) * 16 + lkg * 4 + q)) * 8 + (l15 & 7)] =
            f2bf(hn);
      }
    }
    __syncthreads();
    hb ^= 1;

    if (w < 4) {                // fused out-proj on h[t] (= hfrag[hb])
      const unsigned short* hrd2 = hfrag + hb * 4096;
      f32x4 oa = {bo, bo, bo, bo};
#pragma unroll
      for (int kt = 0; kt < 8; ++kt) {
        bf16x8 h2 = *(const bf16x8*)&hrd2[(kt * 64 + lane) * 8];
        bf16x8 wf;
        if (kt < 3) wf = *(const bf16x8*)&woutlds[((kt * 4 + w) * 64 + lane) * 8];
        else        wf = wop[kt - 3];
        oa = mfma16(h2, wf, oa);
      }
#pragma unroll
      for (int q = 0; q < 4; ++q)
        out[((size_t)(b0 + lkg * 4 + q) * 1024 + t) * 64 + w * 16 + l15] = oa[q];
    }
  }
}

extern "C" void kernel_launch(void* const* d_in, const int* in_sizes, int n_in,
                              void* d_out, int out_size, void* d_ws, size_t ws_size,
                              hipStream_t stream) {
  const float* inputs = (const float*)d_in[0];
  const float* W_enc  = (const float*)d_in[1];
  const float* U_enc  = (const float*)d_in[2];
  const float* b_enc  = (const float*)d_in[3];
  const float* W_dec  = (const float*)d_in[4];
  const float* U_dec  = (const float*)d_in[5];
  const float* b_dec  = (const float*)d_in[6];
  const float* W_out  = (const float*)d_in[7];
  const float* b_out  = (const float*)d_in[8];

  char* ws = (char*)d_ws;
  unsigned short* Uef  = (unsigned short*)(ws + 0);        // 512KB
  unsigned short* Udf  = (unsigned short*)(ws + 524288);   // 512KB
  unsigned short* Wef  = (unsigned short*)(ws + 1048576);  // 256KB
  unsigned short* Wd0f = (unsigned short*)(ws + 1310720);  // 128KB
  unsigned short* WdLf = (unsigned short*)(ws + 1441792);  // 512KB
  unsigned short* Wof  = (unsigned short*)(ws + 1966080);  // 32KB
  unsigned short* hfin = (unsigned short*)(ws + 1998848);  // 128KB
  unsigned int*   flags = (unsigned int*)(ws + 2129920);   // 64KB

  mask_flags<<<1024, 256, 0, stream>>>(inputs, flags);
  pack_frags<<<128, 256, 0, stream>>>(U_enc, Uef, 256, 1024);
  pack_frags<<<128, 256, 0, stream>>>(U_dec, Udf, 256, 1024);
  pack_frags<<<128, 256, 0, stream>>>(W_enc, Wef, 128, 1024);
  pack_frags<<<128, 256, 0, stream>>>(W_dec, Wd0f, 64, 1024);
  pack_frags<<<128, 256, 0, stream>>>(W_dec + 64 * 1024, WdLf, 256, 1024);
  pack_frags<<<32, 256, 0, stream>>>(W_out, Wof, 256, 64);

  enc_rnn<<<16, 512, 0, stream>>>(inputs, Wef, Uef, b_enc, flags, hfin);
  dec_rnn<<<16, 512, 0, stream>>>(inputs, Wd0f, WdLf, Udf, b_dec, Wof, b_out,
                                  hfin, (float*)d_out);
}

// Round 6
// 6163.396 us; speedup vs baseline: 4.3953x; 4.3953x over previous
//
#include <hip/hip_runtime.h>

// RNN-VAE on MI355X. R6: 64 WGs = 16 batch-groups x 4 N-split WGs.
// Each WG owns 256 of 1024 gate-cols (wave w: one 16-col tile per gate ->
// in-register i/f/g/o fusion). U-slice (256x256) fully pinned in LDS (128KB),
// W-slice pinned in regs (16 frags/wave) -> ZERO per-step weight streaming.
// Per step the 4 WGs of a group exchange h (8KB) through the LLC with
// agent-scope atomics + release flag + relaxed spin, parity double-buffered.
// 1 WG/CU, grid 64 <= 256 CUs -> co-resident; spin has a bailout valve.

typedef __bf16 bf16x8 __attribute__((ext_vector_type(8)));
typedef float f32x4 __attribute__((ext_vector_type(4)));
typedef unsigned int uint4v __attribute__((ext_vector_type(4)));
typedef unsigned long long ull;

#define DI __device__ __forceinline__

DI unsigned short f2bf(float f) {            // fp32 -> bf16 RNE
  unsigned int u = __float_as_uint(f);
  u += 0x7fffu + ((u >> 16) & 1u);
  return (unsigned short)(u >> 16);
}
DI float sigf(float v) { return 1.0f / (1.0f + __expf(-v)); }

union FragU { bf16x8 v; unsigned short us[8]; };
union H8 { bf16x8 v; ull u[2]; uint4v q; };

DI f32x4 mfma16(bf16x8 a, bf16x8 b, f32x4 c) {
  // D[row=(lane>>4)*4+q][col=lane&15]; A[row=lane&15][k=(lane>>4)*8+j]
  return __builtin_amdgcn_mfma_f32_16x16x32_bf16(a, b, c, 0, 0, 0);
}

// ---- weight fragment packing: src (K x N fp32, row-major) ->
// frag[j] = src[kt*32+(lane>>4)*8+j][nt*16+(lane&15)], flat idx (kt*NT+nt)*64+lane
__global__ void pack_frags(const float* __restrict__ src,
                           unsigned short* __restrict__ dst, int K, int N) {
  int KT = K >> 5, NT = N >> 4;
  int total = KT * NT * 64;
  for (int idx = blockIdx.x * blockDim.x + threadIdx.x; idx < total;
       idx += gridDim.x * blockDim.x) {
    int lane = idx & 63;
    int fi = idx >> 6;
    int nt = fi % NT;
    int kt = fi / NT;
    int r0 = kt * 32 + (lane >> 4) * 8;
    int col = nt * 16 + (lane & 15);
    unsigned int w[4];
#pragma unroll
    for (int p = 0; p < 4; ++p) {
      unsigned int lo = f2bf(src[(size_t)(r0 + 2 * p) * N + col]);
      unsigned int hi = f2bf(src[(size_t)(r0 + 2 * p + 1) * N + col]);
      w[p] = lo | (hi << 16);
    }
    *(uint4v*)(dst + (size_t)idx * 8) = (uint4v){w[0], w[1], w[2], w[3]};
  }
}

// ---- per-(b,t) nonzero mask: fmask[b>>4][t] bit (b&15) ----
__global__ void mask_flags(const float* __restrict__ x,
                           unsigned int* __restrict__ fmask) {
  const int t = blockIdx.x;
  const int b = threadIdx.x;
  const float* p = x + ((size_t)b * 1024 + t) * 128;
  bool nz = false;
#pragma unroll 8
  for (int k = 0; k < 32; ++k) {
    float4 v = *(const float4*)(p + k * 4);
    nz = nz || v.x != 0.f || v.y != 0.f || v.z != 0.f || v.w != 0.f;
  }
  unsigned long long bal = __ballot((int)nz);
  if ((threadIdx.x & 15) == 0)
    fmask[(size_t)(b >> 4) * 1024 + t] =
        (unsigned int)((bal >> (threadIdx.x & 48)) & 0xFFFFull);
}

#define LOAD_ULDS(SRC) do {                                                 \
    _Pragma("unroll")                                                       \
    for (int vv = 0; vv < 32; ++vv) {                                       \
      int flat = vv * 256 + tid;                                            \
      int kt_ = flat >> 10, ntl = (flat >> 6) & 15, ln = flat & 63;         \
      int nt_ = (ntl >> 2) * 16 + s * 4 + (ntl & 3);                        \
      ((uint4v*)ulds)[flat] = ((const uint4v*)(SRC))[(kt_ * 64 + nt_) * 64 + ln]; \
    } } while (0)

// exchange: store 4 h vals (agent atomics), flag++, spin, reload hfr[8]
#define EXCHANGE(HX, FLAG, TIDX) do {                                       \
    __syncthreads();                                                        \
    if (tid == 0) {                                                         \
      __hip_atomic_fetch_add(&(FLAG)[g * 1024 + (TIDX)], 1u,                \
                             __ATOMIC_RELEASE, __HIP_MEMORY_SCOPE_AGENT);   \
      unsigned it = 0;                                                      \
      while (__hip_atomic_load(&(FLAG)[g * 1024 + (TIDX)],                  \
                 __ATOMIC_RELAXED, __HIP_MEMORY_SCOPE_AGENT) < 4u) {        \
        __builtin_amdgcn_s_sleep(1);                                        \
        if (++it > (1u << 16)) break;                                       \
      }                                                                     \
    }                                                                       \
    __syncthreads();                                                        \
    const ull* hxr = (const ull*)((HX) + ((size_t)g * 2 + pb) * 4096);      \
    _Pragma("unroll")                                                       \
    for (int kt_ = 0; kt_ < 8; ++kt_) {                                     \
      H8 hh_;                                                               \
      hh_.u[0] = __hip_atomic_load(&hxr[(kt_ * 64 + lane) * 2],             \
                     __ATOMIC_RELAXED, __HIP_MEMORY_SCOPE_AGENT);           \
      hh_.u[1] = __hip_atomic_load(&hxr[(kt_ * 64 + lane) * 2 + 1],         \
                     __ATOMIC_RELAXED, __HIP_MEMORY_SCOPE_AGENT);           \
      hfr[kt_] = hh_.v;                                                     \
    }                                                                       \
    pb ^= 1;                                                                \
  } while (0)

// =========================== encoder ======================================
__global__ __launch_bounds__(256) __attribute__((amdgpu_waves_per_eu(1, 1)))
void enc_rnn(const float* __restrict__ x,
             const unsigned short* __restrict__ Wef,   // 128x1024 frags
             const unsigned short* __restrict__ Uef,   // 256x1024 frags
             const float* __restrict__ benc,
             const unsigned int* __restrict__ fmask,
             unsigned short* __restrict__ hxE,         // [16][2][4096]
             unsigned int* __restrict__ flagE,         // [16][1024]
             unsigned short* __restrict__ hfin) {      // [16][8][64][8]
  __shared__ __align__(16) unsigned short ulds[8 * 16 * 64 * 8];  // 128KB

  const int tid = threadIdx.x;
  const int w = tid >> 6, lane = tid & 63;
  const int l15 = lane & 15, lkg = lane >> 4;
  const int bid = blockIdx.x;
  const int s = bid >> 4, g = bid & 15;      // group WGs {g,16+g,32+g,48+g}
  const int b0 = g * 16;
  int ntf[4];
#pragma unroll
  for (int G = 0; G < 4; ++G) ntf[G] = G * 16 + s * 4 + w;

  LOAD_ULDS(Uef);

  const bf16x8* Wl = (const bf16x8*)Wef + lane;
  bf16x8 wpin[4][4];                          // W kt0..3 x 4 gates
#pragma unroll
  for (int G = 0; G < 4; ++G)
#pragma unroll
    for (int kt = 0; kt < 4; ++kt) wpin[G][kt] = Wl[(kt * 64 + ntf[G]) * 64];

  float bfr[4];
#pragma unroll
  for (int G = 0; G < 4; ++G) bfr[G] = benc[ntf[G] * 16 + l15];

  float c4[4];
  unsigned short hreg[4];
  bf16x8 hfr[8];
#pragma unroll
  for (int q = 0; q < 4; ++q) { c4[q] = 0.f; hreg[q] = 0; }
  H8 z_; z_.u[0] = 0; z_.u[1] = 0;
#pragma unroll
  for (int kt = 0; kt < 8; ++kt) hfr[kt] = z_.v;

  const float* xbase = x + (size_t)(b0 + l15) * 1024 * 128 + lkg * 8;
  const unsigned int* flagp = fmask + (size_t)g * 1024;
  const int ktst = 2 * s + (w >> 1);
  const int lbase = (w & 1) * 32 + (l15 >> 3) * 16 + lkg * 4;
  const int jst = l15 & 7;
  int pb = 0;

  __syncthreads();

  for (int t = 0; t < 1024; ++t) {
    const unsigned int flag_t = flagp[t];
    if (flag_t == 0u) continue;              // uniform skip: carry h,c

    const float* xp = xbase + (size_t)t * 128;
    float4 xa[4][2];
#pragma unroll
    for (int kt = 0; kt < 4; ++kt) {          // issue x loads first
      xa[kt][0] = *(const float4*)(xp + kt * 32);
      xa[kt][1] = *(const float4*)(xp + kt * 32 + 4);
    }

    f32x4 acc[4];
#pragma unroll
    for (int G = 0; G < 4; ++G) acc[G] = (f32x4){bfr[G], bfr[G], bfr[G], bfr[G]};

    // U-part (LDS pinned) — hides x-load latency
#pragma unroll
    for (int kt = 0; kt < 8; ++kt)
#pragma unroll
      for (int G = 0; G < 4; ++G) {
        bf16x8 u_ = *(const bf16x8*)&ulds[(size_t)(((kt * 16 + G * 4 + w) * 64 + lane)) * 8];
        acc[G] = mfma16(hfr[kt], u_, acc[G]);
      }

    // x-part (reg pinned)
    FragU xf[4];
#pragma unroll
    for (int kt = 0; kt < 4; ++kt) {
      xf[kt].us[0] = f2bf(xa[kt][0].x); xf[kt].us[1] = f2bf(xa[kt][0].y);
      xf[kt].us[2] = f2bf(xa[kt][0].z); xf[kt].us[3] = f2bf(xa[kt][0].w);
      xf[kt].us[4] = f2bf(xa[kt][1].x); xf[kt].us[5] = f2bf(xa[kt][1].y);
      xf[kt].us[6] = f2bf(xa[kt][1].z); xf[kt].us[7] = f2bf(xa[kt][1].w);
    }
#pragma unroll
    for (int kt = 0; kt < 4; ++kt)
#pragma unroll
      for (int G = 0; G < 4; ++G) acc[G] = mfma16(xf[kt].v, wpin[G][kt], acc[G]);

    // gate fusion + h store (agent atomics into parity buffer)
    unsigned short* hxw = hxE + ((size_t)g * 2 + pb) * 4096;
#pragma unroll
    for (int q = 0; q < 4; ++q) {
      float iv = sigf(acc[0][q]);
      float fv = sigf(acc[1][q]);
      float gv = fmaxf(acc[2][q], 0.f);
      float ov = sigf(acc[3][q]);
      float cn = fv * c4[q] + iv * gv;
      float hn = ov * fmaxf(cn, 0.f);
      bool m = (flag_t >> (lkg * 4 + q)) & 1u;
      c4[q] = m ? cn : c4[q];
      unsigned short hh = m ? f2bf(hn) : hreg[q];
      hreg[q] = hh;
      __hip_atomic_store(&hxw[(ktst * 64 + lbase + q) * 8 + jst], hh,
                         __ATOMIC_RELAXED, __HIP_MEMORY_SCOPE_AGENT);
    }

    EXCHANGE(hxE, flagE, t);
  }

  if (w < 2) {                               // write own h_fin kt slices
    int kt = 2 * s + w;
    H8 hh_; hh_.v = hfr[kt];
    *(uint4v*)&hfin[((size_t)g * 8 + kt) * 512 + lane * 8] = hh_.q;
  }
}

// =========================== decoder ======================================
__global__ __launch_bounds__(256) __attribute__((amdgpu_waves_per_eu(1, 1)))
void dec_rnn(const float* __restrict__ x,
             const unsigned short* __restrict__ Wd0f,   // 64x1024 frags
             const unsigned short* __restrict__ WdLf,   // 256x1024 frags
             const unsigned short* __restrict__ Udf,    // 256x1024 frags
             const float* __restrict__ bdec,
             const unsigned short* __restrict__ Wof,    // 256x64 frags (NT=4)
             const float* __restrict__ bout,
             const unsigned short* __restrict__ hfin,
             unsigned short* __restrict__ hxD,
             unsigned int* __restrict__ flagD,
             float* __restrict__ out) {
  __shared__ __align__(16) unsigned short ulds[8 * 16 * 64 * 8];  // 128KB

  const int tid = threadIdx.x;
  const int w = tid >> 6, lane = tid & 63;
  const int l15 = lane & 15, lkg = lane >> 4;
  const int bid = blockIdx.x;
  const int s = bid >> 4, g = bid & 15;
  const int b0 = g * 16;
  int ntf[4];
#pragma unroll
  for (int G = 0; G < 4; ++G) ntf[G] = G * 16 + s * 4 + w;

  LOAD_ULDS(Udf);

  const bf16x8* W0l = (const bf16x8*)Wd0f + lane;
  const bf16x8* WLl = (const bf16x8*)WdLf + lane;
  bf16x8 w0pin[4][2];
#pragma unroll
  for (int G = 0; G < 4; ++G)
#pragma unroll
    for (int kt = 0; kt < 2; ++kt) w0pin[G][kt] = W0l[(kt * 64 + ntf[G]) * 64];

  // lat[G] = b_dec + h_fin @ W_dec[64:]  (init-only, streamed)
  f32x4 lat[4];
  {
    bf16x8 ha[8];
#pragma unroll
    for (int kt = 0; kt < 8; ++kt)
      ha[kt] = *(const bf16x8*)&hfin[((size_t)g * 8 + kt) * 512 + lane * 8];
#pragma unroll
    for (int G = 0; G < 4; ++G) {
      float bd = bdec[ntf[G] * 16 + l15];
      lat[G] = (f32x4){bd, bd, bd, bd};
    }
#pragma unroll
    for (int kt = 0; kt < 8; ++kt)
#pragma unroll
      for (int G = 0; G < 4; ++G)
        lat[G] = mfma16(ha[kt], WLl[(kt * 64 + ntf[G]) * 64], lat[G]);
  }

  bf16x8 wofr[8];                            // W_out cols s*16.. (wave 0 only)
  if (w == 0) {
#pragma unroll
    for (int kt = 0; kt < 8; ++kt)
      wofr[kt] = ((const bf16x8*)Wof)[(kt * 4 + s) * 64 + lane];
  }
  const float bo = bout[s * 16 + l15];

  float c4[4];
  bf16x8 hfr[8];
#pragma unroll
  for (int q = 0; q < 4; ++q) c4[q] = 0.f;
  H8 z_; z_.u[0] = 0; z_.u[1] = 0;
#pragma unroll
  for (int kt = 0; kt < 8; ++kt) hfr[kt] = z_.v;

  const float* xbase = x + (size_t)(b0 + l15) * 1024 * 128 + lkg * 8;
  const int ktst = 2 * s + (w >> 1);
  const int lbase = (w & 1) * 32 + (l15 >> 3) * 16 + lkg * 4;
  const int jst = l15 & 7;
  int pb = 0;

  __syncthreads();

  for (int t = 0; t < 1024; ++t) {
    const float* xp = xbase + (size_t)t * 128;
    float4 xa[2][2];
#pragma unroll
    for (int kt = 0; kt < 2; ++kt) {
      xa[kt][0] = *(const float4*)(xp + kt * 32);
      xa[kt][1] = *(const float4*)(xp + kt * 32 + 4);
    }

    f32x4 acc[4];
#pragma unroll
    for (int G = 0; G < 4; ++G) acc[G] = lat[G];

#pragma unroll
    for (int kt = 0; kt < 8; ++kt)
#pragma unroll
      for (int G = 0; G < 4; ++G) {
        bf16x8 u_ = *(const bf16x8*)&ulds[(size_t)(((kt * 16 + G * 4 + w) * 64 + lane)) * 8];
        acc[G] = mfma16(hfr[kt], u_, acc[G]);
      }

    FragU xf[2];
#pragma unroll
    for (int kt = 0; kt < 2; ++kt) {
      xf[kt].us[0] = f2bf(xa[kt][0].x); xf[kt].us[1] = f2bf(xa[kt][0].y);
      xf[kt].us[2] = f2bf(xa[kt][0].z); xf[kt].us[3] = f2bf(xa[kt][0].w);
      xf[kt].us[4] = f2bf(xa[kt][1].x); xf[kt].us[5] = f2bf(xa[kt][1].y);
      xf[kt].us[6] = f2bf(xa[kt][1].z); xf[kt].us[7] = f2bf(xa[kt][1].w);
    }
#pragma unroll
    for (int kt = 0; kt < 2; ++kt)
#pragma unroll
      for (int G = 0; G < 4; ++G) acc[G] = mfma16(xf[kt].v, w0pin[G][kt], acc[G]);

    unsigned short* hxw = hxD + ((size_t)g * 2 + pb) * 4096;
#pragma unroll
    for (int q = 0; q < 4; ++q) {
      float iv = sigf(acc[0][q]);
      float fv = sigf(acc[1][q]);
      float gv = fmaxf(acc[2][q], 0.f);
      float ov = sigf(acc[3][q]);
      float cn = fv * c4[q] + iv * gv;
      float hn = ov * fmaxf(cn, 0.f);
      c4[q] = cn;
      __hip_atomic_store(&hxw[(ktst * 64 + lbase + q) * 8 + jst], f2bf(hn),
                         __ATOMIC_RELAXED, __HIP_MEMORY_SCOPE_AGENT);
    }

    EXCHANGE(hxD, flagD, t);

    if (w == 0) {              // fused out-proj: out[b,t,:16 cols @ s]
      f32x4 oa = {bo, bo, bo, bo};
#pragma unroll
      for (int kt = 0; kt < 8; ++kt) oa = mfma16(hfr[kt], wofr[kt], oa);
#pragma unroll
      for (int q = 0; q < 4; ++q)
        out[((size_t)(b0 + lkg * 4 + q) * 1024 + t) * 64 + s * 16 + l15] = oa[q];
    }
  }
}

extern "C" void kernel_launch(void* const* d_in, const int* in_sizes, int n_in,
                              void* d_out, int out_size, void* d_ws, size_t ws_size,
                              hipStream_t stream) {
  const float* inputs = (const float*)d_in[0];
  const float* W_enc  = (const float*)d_in[1];
  const float* U_enc  = (const float*)d_in[2];
  const float* b_enc  = (const float*)d_in[3];
  const float* W_dec  = (const float*)d_in[4];
  const float* U_dec  = (const float*)d_in[5];
  const float* b_dec  = (const float*)d_in[6];
  const float* W_out  = (const float*)d_in[7];
  const float* b_out  = (const float*)d_in[8];

  char* ws = (char*)d_ws;
  unsigned short* Uef   = (unsigned short*)(ws + 0);        // 512K
  unsigned short* Udf   = (unsigned short*)(ws + 524288);   // 512K
  unsigned short* Wef   = (unsigned short*)(ws + 1048576);  // 256K
  unsigned short* Wd0f  = (unsigned short*)(ws + 1310720);  // 128K
  unsigned short* WdLf  = (unsigned short*)(ws + 1441792);  // 512K
  unsigned short* Wof   = (unsigned short*)(ws + 1966080);  // 32K
  unsigned short* hfin  = (unsigned short*)(ws + 1998848);  // 128K
  unsigned int*   fmask = (unsigned int*)(ws + 2129920);    // 64K
  unsigned int*   flagE = (unsigned int*)(ws + 2195456);    // 64K
  unsigned int*   flagD = (unsigned int*)(ws + 2260992);    // 64K
  unsigned short* hxE   = (unsigned short*)(ws + 2326528);  // 256K
  unsigned short* hxD   = (unsigned short*)(ws + 2588672);  // 256K

  hipMemsetAsync(ws + 2195456, 0, 131072, stream);          // flagE+flagD

  mask_flags<<<1024, 256, 0, stream>>>(inputs, fmask);
  pack_frags<<<128, 256, 0, stream>>>(U_enc, Uef, 256, 1024);
  pack_frags<<<128, 256, 0, stream>>>(U_dec, Udf, 256, 1024);
  pack_frags<<<128, 256, 0, stream>>>(W_enc, Wef, 128, 1024);
  pack_frags<<<128, 256, 0, stream>>>(W_dec, Wd0f, 64, 1024);
  pack_frags<<<128, 256, 0, stream>>>(W_dec + 64 * 1024, WdLf, 256, 1024);
  pack_frags<<<32, 256, 0, stream>>>(W_out, Wof, 256, 64);

  enc_rnn<<<64, 256, 0, stream>>>(inputs, Wef, Uef, b_enc, fmask,
                                  hxE, flagE, hfin);
  dec_rnn<<<64, 256, 0, stream>>>(inputs, Wd0f, WdLf, Udf, b_dec, Wof, b_out,
                                  hfin, hxD, flagD, (float*)d_out);
}

// Round 7
// 5977.629 us; speedup vs baseline: 4.5319x; 1.0311x over previous
//
#include <hip/hip_runtime.h>

// RNN-VAE on MI355X. R7: 64 WGs = 16 batch-groups x 4 N-split WGs (as R6:
// U-slice LDS-pinned 128KB, W-slice reg-pinned, zero per-step weight
// streaming). Exchange compressed: per-thread spin on wave-uniform flag
// (no tid0 relay, no 2nd barrier) -> ~2 LLC RTs; spin window filled with
// out-proj(t-1) (dec) and x[t+1] prefetch (both), so HBM x-latency and
// out-proj MFMAs leave the critical path.

typedef __bf16 bf16x8 __attribute__((ext_vector_type(8)));
typedef float f32x4 __attribute__((ext_vector_type(4)));
typedef unsigned int uint4v __attribute__((ext_vector_type(4)));
typedef unsigned long long ull;

#define DI __device__ __forceinline__

DI unsigned short f2bf(float f) {            // fp32 -> bf16 RNE
  unsigned int u = __float_as_uint(f);
  u += 0x7fffu + ((u >> 16) & 1u);
  return (unsigned short)(u >> 16);
}
DI float sigf(float v) { return 1.0f / (1.0f + __expf(-v)); }

union FragU { bf16x8 v; unsigned short us[8]; };
union H8 { bf16x8 v; ull u[2]; uint4v q; };

DI f32x4 mfma16(bf16x8 a, bf16x8 b, f32x4 c) {
  // D[row=(lane>>4)*4+q][col=lane&15]; A[row=lane&15][k=(lane>>4)*8+j]
  return __builtin_amdgcn_mfma_f32_16x16x32_bf16(a, b, c, 0, 0, 0);
}

// ---- weight fragment packing (unchanged) ----
__global__ void pack_frags(const float* __restrict__ src,
                           unsigned short* __restrict__ dst, int K, int N) {
  int KT = K >> 5, NT = N >> 4;
  int total = KT * NT * 64;
  for (int idx = blockIdx.x * blockDim.x + threadIdx.x; idx < total;
       idx += gridDim.x * blockDim.x) {
    int lane = idx & 63;
    int fi = idx >> 6;
    int nt = fi % NT;
    int kt = fi / NT;
    int r0 = kt * 32 + (lane >> 4) * 8;
    int col = nt * 16 + (lane & 15);
    unsigned int w[4];
#pragma unroll
    for (int p = 0; p < 4; ++p) {
      unsigned int lo = f2bf(src[(size_t)(r0 + 2 * p) * N + col]);
      unsigned int hi = f2bf(src[(size_t)(r0 + 2 * p + 1) * N + col]);
      w[p] = lo | (hi << 16);
    }
    *(uint4v*)(dst + (size_t)idx * 8) = (uint4v){w[0], w[1], w[2], w[3]};
  }
}

// ---- per-(b,t) nonzero mask (unchanged) ----
__global__ void mask_flags(const float* __restrict__ x,
                           unsigned int* __restrict__ fmask) {
  const int t = blockIdx.x;
  const int b = threadIdx.x;
  const float* p = x + ((size_t)b * 1024 + t) * 128;
  bool nz = false;
#pragma unroll 8
  for (int k = 0; k < 32; ++k) {
    float4 v = *(const float4*)(p + k * 4);
    nz = nz || v.x != 0.f || v.y != 0.f || v.z != 0.f || v.w != 0.f;
  }
  unsigned long long bal = __ballot((int)nz);
  if ((threadIdx.x & 15) == 0)
    fmask[(size_t)(b >> 4) * 1024 + t] =
        (unsigned int)((bal >> (threadIdx.x & 48)) & 0xFFFFull);
}

#define LOAD_ULDS(SRC) do {                                                 \
    _Pragma("unroll")                                                       \
    for (int vv = 0; vv < 32; ++vv) {                                       \
      int flat = vv * 256 + tid;                                            \
      int kt_ = flat >> 10, ntl = (flat >> 6) & 15, ln = flat & 63;         \
      int nt_ = (ntl >> 2) * 16 + s * 4 + (ntl & 3);                        \
      ((uint4v*)ulds)[flat] = ((const uint4v*)(SRC))[(kt_ * 64 + nt_) * 64 + ln]; \
    } } while (0)

// signal: local barrier (orders all WG stores) + one release add by tid0
#define EXCH_SIGNAL(FLAG, TIDX) do {                                        \
    __syncthreads();                                                        \
    if (tid == 0)                                                           \
      __hip_atomic_fetch_add(&(FLAG)[g * 1024 + (TIDX)], 1u,                \
                             __ATOMIC_RELEASE, __HIP_MEMORY_SCOPE_AGENT);   \
  } while (0)

// wait: every thread spins on wave-uniform flag addr, then loads its slices
#define EXCH_WAIT(HX, FLAG, TIDX) do {                                      \
    unsigned it_ = 0;                                                       \
    while (__hip_atomic_load(&(FLAG)[g * 1024 + (TIDX)],                    \
               __ATOMIC_RELAXED, __HIP_MEMORY_SCOPE_AGENT) < 4u) {          \
      if (++it_ > (1u << 12)) break;                                        \
    }                                                                       \
    const ull* hxr = (const ull*)((HX) + ((size_t)g * 2 + pb) * 4096);      \
    _Pragma("unroll")                                                       \
    for (int kt_ = 0; kt_ < 8; ++kt_) {                                     \
      H8 hh_;                                                               \
      hh_.u[0] = __hip_atomic_load(&hxr[(kt_ * 64 + lane) * 2],             \
                     __ATOMIC_RELAXED, __HIP_MEMORY_SCOPE_AGENT);           \
      hh_.u[1] = __hip_atomic_load(&hxr[(kt_ * 64 + lane) * 2 + 1],         \
                     __ATOMIC_RELAXED, __HIP_MEMORY_SCOPE_AGENT);           \
      hfr[kt_] = hh_.v;                                                     \
    }                                                                       \
    pb ^= 1;                                                                \
  } while (0)

// =========================== encoder ======================================
__global__ __launch_bounds__(256) __attribute__((amdgpu_waves_per_eu(1, 1)))
void enc_rnn(const float* __restrict__ x,
             const unsigned short* __restrict__ Wef,
             const unsigned short* __restrict__ Uef,
             const float* __restrict__ benc,
             const unsigned int* __restrict__ fmask,
             unsigned short* __restrict__ hxE,         // [16][2][4096]
             unsigned int* __restrict__ flagE,         // [16][1024]
             unsigned short* __restrict__ hfin) {      // [16][8][64][8]
  __shared__ __align__(16) unsigned short ulds[8 * 16 * 64 * 8];  // 128KB

  const int tid = threadIdx.x;
  const int w = tid >> 6, lane = tid & 63;
  const int l15 = lane & 15, lkg = lane >> 4;
  const int bid = blockIdx.x;
  const int s = bid >> 4, g = bid & 15;
  const int b0 = g * 16;
  int ntf[4];
#pragma unroll
  for (int G = 0; G < 4; ++G) ntf[G] = G * 16 + s * 4 + w;

  LOAD_ULDS(Uef);

  const bf16x8* Wl = (const bf16x8*)Wef + lane;
  bf16x8 wpin[4][4];
#pragma unroll
  for (int G = 0; G < 4; ++G)
#pragma unroll
    for (int kt = 0; kt < 4; ++kt) wpin[G][kt] = Wl[(kt * 64 + ntf[G]) * 64];

  float bfr[4];
#pragma unroll
  for (int G = 0; G < 4; ++G) bfr[G] = benc[ntf[G] * 16 + l15];

  float c4[4];
  unsigned short hreg[4];
  bf16x8 hfr[8];
#pragma unroll
  for (int q = 0; q < 4; ++q) { c4[q] = 0.f; hreg[q] = 0; }
  H8 z_; z_.u[0] = 0; z_.u[1] = 0;
#pragma unroll
  for (int kt = 0; kt < 8; ++kt) hfr[kt] = z_.v;

  const float* xbase = x + (size_t)(b0 + l15) * 1024 * 128 + lkg * 8;
  const unsigned int* flagp = fmask + (size_t)g * 1024;
  const int ktst = 2 * s + (w >> 1);
  const int lbase = (w & 1) * 32 + (l15 >> 3) * 16 + lkg * 4;
  const int jst = l15 & 7;
  int pb = 0;
  bool xvalid = false;
  float4 xa[4][2];

  __syncthreads();

  for (int t = 0; t < 1024; ++t) {
    const unsigned int flag_t = flagp[t];
    if (flag_t == 0u) { xvalid = false; continue; }   // uniform skip

    if (!xvalid) {
      const float* xp = xbase + (size_t)t * 128;
#pragma unroll
      for (int kt = 0; kt < 4; ++kt) {
        xa[kt][0] = *(const float4*)(xp + kt * 32);
        xa[kt][1] = *(const float4*)(xp + kt * 32 + 4);
      }
    }

    f32x4 acc[4];
#pragma unroll
    for (int G = 0; G < 4; ++G) acc[G] = (f32x4){bfr[G], bfr[G], bfr[G], bfr[G]};

    // U-part first (hides x-load latency when loaded inline)
#pragma unroll
    for (int kt = 0; kt < 8; ++kt)
#pragma unroll
      for (int G = 0; G < 4; ++G) {
        bf16x8 u_ = *(const bf16x8*)&ulds[(size_t)(((kt * 16 + G * 4 + w) * 64 + lane)) * 8];
        acc[G] = mfma16(hfr[kt], u_, acc[G]);
      }

    FragU xf[4];
#pragma unroll
    for (int kt = 0; kt < 4; ++kt) {
      xf[kt].us[0] = f2bf(xa[kt][0].x); xf[kt].us[1] = f2bf(xa[kt][0].y);
      xf[kt].us[2] = f2bf(xa[kt][0].z); xf[kt].us[3] = f2bf(xa[kt][0].w);
      xf[kt].us[4] = f2bf(xa[kt][1].x); xf[kt].us[5] = f2bf(xa[kt][1].y);
      xf[kt].us[6] = f2bf(xa[kt][1].z); xf[kt].us[7] = f2bf(xa[kt][1].w);
    }
#pragma unroll
    for (int kt = 0; kt < 4; ++kt)
#pragma unroll
      for (int G = 0; G < 4; ++G) acc[G] = mfma16(xf[kt].v, wpin[G][kt], acc[G]);

    // gates + h store into parity buffer
    unsigned short* hxw = hxE + ((size_t)g * 2 + pb) * 4096;
#pragma unroll
    for (int q = 0; q < 4; ++q) {
      float iv = sigf(acc[0][q]);
      float fv = sigf(acc[1][q]);
      float gv = fmaxf(acc[2][q], 0.f);
      float ov = sigf(acc[3][q]);
      float cn = fv * c4[q] + iv * gv;
      float hn = ov * fmaxf(cn, 0.f);
      bool m = (flag_t >> (lkg * 4 + q)) & 1u;
      c4[q] = m ? cn : c4[q];
      unsigned short hh = m ? f2bf(hn) : hreg[q];
      hreg[q] = hh;
      __hip_atomic_store(&hxw[(ktst * 64 + lbase + q) * 8 + jst], hh,
                         __ATOMIC_RELAXED, __HIP_MEMORY_SCOPE_AGENT);
    }

    EXCH_SIGNAL(flagE, t);

    // spin-window overlap: prefetch x[t+1]
    if (t < 1023) {
      const float* xq = xbase + (size_t)(t + 1) * 128;
#pragma unroll
      for (int kt = 0; kt < 4; ++kt) {
        xa[kt][0] = *(const float4*)(xq + kt * 32);
        xa[kt][1] = *(const float4*)(xq + kt * 32 + 4);
      }
      xvalid = true;
    } else xvalid = false;

    EXCH_WAIT(hxE, flagE, t);
  }

  if (w < 2) {
    int kt = 2 * s + w;
    H8 hh_; hh_.v = hfr[kt];
    *(uint4v*)&hfin[((size_t)g * 8 + kt) * 512 + lane * 8] = hh_.q;
  }
}

// =========================== decoder ======================================
__global__ __launch_bounds__(256) __attribute__((amdgpu_waves_per_eu(1, 1)))
void dec_rnn(const float* __restrict__ x,
             const unsigned short* __restrict__ Wd0f,
             const unsigned short* __restrict__ WdLf,
             const unsigned short* __restrict__ Udf,
             const float* __restrict__ bdec,
             const unsigned short* __restrict__ Wof,
             const float* __restrict__ bout,
             const unsigned short* __restrict__ hfin,
             unsigned short* __restrict__ hxD,
             unsigned int* __restrict__ flagD,
             float* __restrict__ out) {
  __shared__ __align__(16) unsigned short ulds[8 * 16 * 64 * 8];  // 128KB

  const int tid = threadIdx.x;
  const int w = tid >> 6, lane = tid & 63;
  const int l15 = lane & 15, lkg = lane >> 4;
  const int bid = blockIdx.x;
  const int s = bid >> 4, g = bid & 15;
  const int b0 = g * 16;
  int ntf[4];
#pragma unroll
  for (int G = 0; G < 4; ++G) ntf[G] = G * 16 + s * 4 + w;

  LOAD_ULDS(Udf);

  const bf16x8* W0l = (const bf16x8*)Wd0f + lane;
  const bf16x8* WLl = (const bf16x8*)WdLf + lane;
  bf16x8 w0pin[4][2];
#pragma unroll
  for (int G = 0; G < 4; ++G)
#pragma unroll
    for (int kt = 0; kt < 2; ++kt) w0pin[G][kt] = W0l[(kt * 64 + ntf[G]) * 64];

  f32x4 lat[4];
  {
    bf16x8 ha[8];
#pragma unroll
    for (int kt = 0; kt < 8; ++kt)
      ha[kt] = *(const bf16x8*)&hfin[((size_t)g * 8 + kt) * 512 + lane * 8];
#pragma unroll
    for (int G = 0; G < 4; ++G) {
      float bd = bdec[ntf[G] * 16 + l15];
      lat[G] = (f32x4){bd, bd, bd, bd};
    }
#pragma unroll
    for (int kt = 0; kt < 8; ++kt)
#pragma unroll
      for (int G = 0; G < 4; ++G)
        lat[G] = mfma16(ha[kt], WLl[(kt * 64 + ntf[G]) * 64], lat[G]);
  }

  bf16x8 wofr[8];
  if (w == 0) {
#pragma unroll
    for (int kt = 0; kt < 8; ++kt)
      wofr[kt] = ((const bf16x8*)Wof)[(kt * 4 + s) * 64 + lane];
  }
  const float bo = bout[s * 16 + l15];

  float c4[4];
  bf16x8 hfr[8];
#pragma unroll
  for (int q = 0; q < 4; ++q) c4[q] = 0.f;
  H8 z_; z_.u[0] = 0; z_.u[1] = 0;
#pragma unroll
  for (int kt = 0; kt < 8; ++kt) hfr[kt] = z_.v;

  const float* xbase = x + (size_t)(b0 + l15) * 1024 * 128 + lkg * 8;
  const int ktst = 2 * s + (w >> 1);
  const int lbase = (w & 1) * 32 + (l15 >> 3) * 16 + lkg * 4;
  const int jst = l15 & 7;
  int pb = 0;

  float4 xa[2][2];
  xa[0][0] = *(const float4*)(xbase);      xa[0][1] = *(const float4*)(xbase + 4);
  xa[1][0] = *(const float4*)(xbase + 32); xa[1][1] = *(const float4*)(xbase + 36);

  __syncthreads();

  for (int t = 0; t < 1024; ++t) {
    f32x4 acc[4];
#pragma unroll
    for (int G = 0; G < 4; ++G) acc[G] = lat[G];

#pragma unroll
    for (int kt = 0; kt < 8; ++kt)
#pragma unroll
      for (int G = 0; G < 4; ++G) {
        bf16x8 u_ = *(const bf16x8*)&ulds[(size_t)(((kt * 16 + G * 4 + w) * 64 + lane)) * 8];
        acc[G] = mfma16(hfr[kt], u_, acc[G]);
      }

    FragU xf[2];
#pragma unroll
    for (int kt = 0; kt < 2; ++kt) {
      xf[kt].us[0] = f2bf(xa[kt][0].x); xf[kt].us[1] = f2bf(xa[kt][0].y);
      xf[kt].us[2] = f2bf(xa[kt][0].z); xf[kt].us[3] = f2bf(xa[kt][0].w);
      xf[kt].us[4] = f2bf(xa[kt][1].x); xf[kt].us[5] = f2bf(xa[kt][1].y);
      xf[kt].us[6] = f2bf(xa[kt][1].z); xf[kt].us[7] = f2bf(xa[kt][1].w);
    }
#pragma unroll
    for (int kt = 0; kt < 2; ++kt)
#pragma unroll
      for (int G = 0; G < 4; ++G) acc[G] = mfma16(xf[kt].v, w0pin[G][kt], acc[G]);

    unsigned short* hxw = hxD + ((size_t)g * 2 + pb) * 4096;
#pragma unroll
    for (int q = 0; q < 4; ++q) {
      float iv = sigf(acc[0][q]);
      float fv = sigf(acc[1][q]);
      float gv = fmaxf(acc[2][q], 0.f);
      float ov = sigf(acc[3][q]);
      float cn = fv * c4[q] + iv * gv;
      float hn = ov * fmaxf(cn, 0.f);
      c4[q] = cn;
      __hip_atomic_store(&hxw[(ktst * 64 + lbase + q) * 8 + jst], f2bf(hn),
                         __ATOMIC_RELAXED, __HIP_MEMORY_SCOPE_AGENT);
    }

    EXCH_SIGNAL(flagD, t);

    // spin-window overlap: out-proj for t-1 (hfr still = h_{t-1}) + x[t+1]
    if (t > 0 && w == 0) {
      f32x4 oa = {bo, bo, bo, bo};
#pragma unroll
      for (int kt = 0; kt < 8; ++kt) oa = mfma16(hfr[kt], wofr[kt], oa);
#pragma unroll
      for (int q = 0; q < 4; ++q)
        out[((size_t)(b0 + lkg * 4 + q) * 1024 + (t - 1)) * 64 + s * 16 + l15] = oa[q];
    }
    if (t < 1023) {
      const float* xq = xbase + (size_t)(t + 1) * 128;
      xa[0][0] = *(const float4*)(xq);      xa[0][1] = *(const float4*)(xq + 4);
      xa[1][0] = *(const float4*)(xq + 32); xa[1][1] = *(const float4*)(xq + 36);
    }

    EXCH_WAIT(hxD, flagD, t);
  }

  if (w == 0) {               // final out-proj: t=1023 (hfr = h_1023)
    f32x4 oa = {bo, bo, bo, bo};
#pragma unroll
    for (int kt = 0; kt < 8; ++kt) oa = mfma16(hfr[kt], wofr[kt], oa);
#pragma unroll
    for (int q = 0; q < 4; ++q)
      out[((size_t)(b0 + lkg * 4 + q) * 1024 + 1023) * 64 + s * 16 + l15] = oa[q];
  }
}

extern "C" void kernel_launch(void* const* d_in, const int* in_sizes, int n_in,
                              void* d_out, int out_size, void* d_ws, size_t ws_size,
                              hipStream_t stream) {
  const float* inputs = (const float*)d_in[0];
  const float* W_enc  = (const float*)d_in[1];
  const float* U_enc  = (const float*)d_in[2];
  const float* b_enc  = (const float*)d_in[3];
  const float* W_dec  = (const float*)d_in[4];
  const float* U_dec  = (const float*)d_in[5];
  const float* b_dec  = (const float*)d_in[6];
  const float* W_out  = (const float*)d_in[7];
  const float* b_out  = (const float*)d_in[8];

  char* ws = (char*)d_ws;
  unsigned short* Uef   = (unsigned short*)(ws + 0);        // 512K
  unsigned short* Udf   = (unsigned short*)(ws + 524288);   // 512K
  unsigned short* Wef   = (unsigned short*)(ws + 1048576);  // 256K
  unsigned short* Wd0f  = (unsigned short*)(ws + 1310720);  // 128K
  unsigned short* WdLf  = (unsigned short*)(ws + 1441792);  // 512K
  unsigned short* Wof   = (unsigned short*)(ws + 1966080);  // 32K
  unsigned short* hfin  = (unsigned short*)(ws + 1998848);  // 128K
  unsigned int*   fmask = (unsigned int*)(ws + 2129920);    // 64K
  unsigned int*   flagE = (unsigned int*)(ws + 2195456);    // 64K
  unsigned int*   flagD = (unsigned int*)(ws + 2260992);    // 64K
  unsigned short* hxE   = (unsigned short*)(ws + 2326528);  // 256K
  unsigned short* hxD   = (unsigned short*)(ws + 2588672);  // 256K

  hipMemsetAsync(ws + 2195456, 0, 131072, stream);          // flagE+flagD

  mask_flags<<<1024, 256, 0, stream>>>(inputs, fmask);
  pack_frags<<<128, 256, 0, stream>>>(U_enc, Uef, 256, 1024);
  pack_frags<<<128, 256, 0, stream>>>(U_dec, Udf, 256, 1024);
  pack_frags<<<128, 256, 0, stream>>>(W_enc, Wef, 128, 1024);
  pack_frags<<<128, 256, 0, stream>>>(W_dec, Wd0f, 64, 1024);
  pack_frags<<<128, 256, 0, stream>>>(W_dec + 64 * 1024, WdLf, 256, 1024);
  pack_frags<<<32, 256, 0, stream>>>(W_out, Wof, 256, 64);

  enc_rnn<<<64, 256, 0, stream>>>(inputs, Wef, Uef, b_enc, fmask,
                                  hxE, flagE, hfin);
  dec_rnn<<<64, 256, 0, stream>>>(inputs, Wd0f, WdLf, Udf, b_dec, Wof, b_out,
                                  hfin, hxD, flagD, (float*)d_out);
}

// Round 8
// 4958.959 us; speedup vs baseline: 5.4628x; 1.2054x over previous
//
#include <hip/hip_runtime.h>

// RNN-VAE on MI355X. R8: 64 WGs = 16 groups x 4 N-split. U-slice fully
// REGISTER-pinned (32 frags/wave, waves_per_eu(1,1) -> 512-reg budget);
// LDS reduced to an 8KB hstage. Exchange via SELF-VALIDATING tagged 8B
// words ({3 bf16 | tag16=a+1}, single-copy-atomic agent stores): no flags,
// no fetch_add, chain = store-land + one poll RT. Wave 1 polls remote
// slices and broadcasts through hstage; wave 0 runs dec out-proj(t-1) in
// the poll window. Parity-2 ring; tags make stale/zero/0xAA data inert.

typedef __bf16 bf16x8 __attribute__((ext_vector_type(8)));
typedef float f32x4 __attribute__((ext_vector_type(4)));
typedef unsigned int uint4v __attribute__((ext_vector_type(4)));
typedef unsigned long long ull;

#define DI __device__ __forceinline__

DI unsigned short f2bf(float f) {            // fp32 -> bf16 RNE
  unsigned int u = __float_as_uint(f);
  u += 0x7fffu + ((u >> 16) & 1u);
  return (unsigned short)(u >> 16);
}
DI float sigf(float v) { return 1.0f / (1.0f + __expf(-v)); }

union FragU { bf16x8 v; unsigned short us[8]; };
union H8 { bf16x8 v; ull u[2]; uint4v q; };

DI f32x4 mfma16(bf16x8 a, bf16x8 b, f32x4 c) {
  // D[row=(lane>>4)*4+q][col=lane&15]; A[row=lane&15][k=(lane>>4)*8+j]
  return __builtin_amdgcn_mfma_f32_16x16x32_bf16(a, b, c, 0, 0, 0);
}

// ---- weight fragment packing (unchanged) ----
__global__ void pack_frags(const float* __restrict__ src,
                           unsigned short* __restrict__ dst, int K, int N) {
  int KT = K >> 5, NT = N >> 4;
  int total = KT * NT * 64;
  for (int idx = blockIdx.x * blockDim.x + threadIdx.x; idx < total;
       idx += gridDim.x * blockDim.x) {
    int lane = idx & 63;
    int fi = idx >> 6;
    int nt = fi % NT;
    int kt = fi / NT;
    int r0 = kt * 32 + (lane >> 4) * 8;
    int col = nt * 16 + (lane & 15);
    unsigned int w[4];
#pragma unroll
    for (int p = 0; p < 4; ++p) {
      unsigned int lo = f2bf(src[(size_t)(r0 + 2 * p) * N + col]);
      unsigned int hi = f2bf(src[(size_t)(r0 + 2 * p + 1) * N + col]);
      w[p] = lo | (hi << 16);
    }
    *(uint4v*)(dst + (size_t)idx * 8) = (uint4v){w[0], w[1], w[2], w[3]};
  }
}

// ---- per-(b,t) nonzero mask (unchanged) ----
__global__ void mask_flags(const float* __restrict__ x,
                           unsigned int* __restrict__ fmask) {
  const int t = blockIdx.x;
  const int b = threadIdx.x;
  const float* p = x + ((size_t)b * 1024 + t) * 128;
  bool nz = false;
#pragma unroll 8
  for (int k = 0; k < 32; ++k) {
    float4 v = *(const float4*)(p + k * 4);
    nz = nz || v.x != 0.f || v.y != 0.f || v.z != 0.f || v.w != 0.f;
  }
  unsigned long long bal = __ballot((int)nz);
  if ((threadIdx.x & 15) == 0)
    fmask[(size_t)(b >> 4) * 1024 + t] =
        (unsigned int)((bal >> (threadIdx.x & 48)) & 0xFFFFull);
}

// pack own hstage word -> 3 tagged ull agent stores (tid<128)
#define STORE_OWN(HX) do {                                                  \
    if (tid < 128) {                                                        \
      const int kth = tid >> 6, word = tid & 63;                            \
      H8 hh; hh.q = *(const uint4v*)&hstage[2 * s + kth][word][0];          \
      const ull tg = (ull)(a + 1);                                          \
      ull A = (hh.u[0] & 0xFFFFFFFFFFFFULL) | (tg << 48);                   \
      ull B = ((hh.u[0] >> 48) | ((hh.u[1] & 0xFFFFFFFFULL) << 16)) |       \
              (tg << 48);                                                   \
      ull C = (hh.u[1] >> 32) | (tg << 32) | (tg << 48);                    \
      ull* p_ = (HX) + (size_t)(g * 2 + (a & 1)) * 1536 +                   \
                ((2 * s + kth) * 64 + word) * 3;                            \
      __hip_atomic_store(p_ + 0, A, __ATOMIC_RELAXED, __HIP_MEMORY_SCOPE_AGENT); \
      __hip_atomic_store(p_ + 1, B, __ATOMIC_RELAXED, __HIP_MEMORY_SCOPE_AGENT); \
      __hip_atomic_store(p_ + 2, C, __ATOMIC_RELAXED, __HIP_MEMORY_SCOPE_AGENT); \
    } } while (0)

// wave 1: poll 6 remote kt-slices until tags==a+1, broadcast into hstage
#define POLL_REMOTE(HX) do {                                                \
    if (w == 1) {                                                           \
      const ull tg = (ull)(a + 1);                                          \
      int rkt[6]; int nr_ = 0;                                              \
      _Pragma("unroll")                                                     \
      for (int s2 = 0; s2 < 4; ++s2)                                        \
        if (s2 != s) { rkt[nr_++] = 2 * s2; rkt[nr_++] = 2 * s2 + 1; }      \
      const ull* hb_ = (HX) + (size_t)(g * 2 + (a & 1)) * 1536;             \
      ull R[6][3];                                                          \
      unsigned it_ = 0;                                                     \
      for (;;) {                                                            \
        _Pragma("unroll")                                                   \
        for (int r = 0; r < 6; ++r) {                                       \
          const ull* p_ = hb_ + (rkt[r] * 64 + lane) * 3;                   \
          R[r][0] = __hip_atomic_load(p_ + 0, __ATOMIC_RELAXED,             \
                                      __HIP_MEMORY_SCOPE_AGENT);            \
          R[r][1] = __hip_atomic_load(p_ + 1, __ATOMIC_RELAXED,             \
                                      __HIP_MEMORY_SCOPE_AGENT);            \
          R[r][2] = __hip_atomic_load(p_ + 2, __ATOMIC_RELAXED,             \
                                      __HIP_MEMORY_SCOPE_AGENT);            \
        }                                                                   \
        bool ok_ = true;                                                    \
        _Pragma("unroll")                                                   \
        for (int r = 0; r < 6; ++r)                                         \
          ok_ = ok_ && ((R[r][0] >> 48) == tg) && ((R[r][1] >> 48) == tg)   \
                    && ((R[r][2] >> 48) == tg);                             \
        if (ok_ || ++it_ > (1u << 14)) break;                               \
      }                                                                     \
      _Pragma("unroll")                                                     \
      for (int r = 0; r < 6; ++r) {                                         \
        H8 hh;                                                              \
        hh.u[0] = (R[r][0] & 0xFFFFFFFFFFFFULL) | (R[r][1] << 48);          \
        hh.u[1] = ((R[r][1] >> 16) & 0xFFFFFFFFULL) |                       \
                  ((R[r][2] & 0xFFFFFFFFULL) << 32);                        \
        *(uint4v*)&hstage[rkt[r]][lane][0] = hh.q;                          \
      }                                                                     \
    } } while (0)

// =========================== encoder ======================================
__global__ __launch_bounds__(256) __attribute__((amdgpu_waves_per_eu(1, 1)))
void enc_rnn(const float* __restrict__ x,
             const unsigned short* __restrict__ Wef,
             const unsigned short* __restrict__ Uef,
             const float* __restrict__ benc,
             const unsigned int* __restrict__ fmask,
             ull* __restrict__ hxE,                    // [16][2][512][3] ull
             unsigned short* __restrict__ hfin) {
  __shared__ __align__(16) unsigned short hstage[8][64][8];   // 8KB

  const int tid = threadIdx.x;
  const int w = tid >> 6, lane = tid & 63;
  const int l15 = lane & 15, lkg = lane >> 4;
  const int bid = blockIdx.x;
  const int s = bid >> 4, g = bid & 15;
  const int b0 = g * 16;
  int ntf[4];
#pragma unroll
  for (int G = 0; G < 4; ++G) ntf[G] = G * 16 + s * 4 + w;

  const bf16x8* Wl = (const bf16x8*)Wef + lane;
  const bf16x8* Ul = (const bf16x8*)Uef + lane;
  const unsigned int* flagp = fmask + (size_t)g * 1024;

  bf16x8 upin[8][4];                         // full U slice in registers
#pragma unroll
  for (int kt = 0; kt < 8; ++kt)
#pragma unroll
    for (int G = 0; G < 4; ++G) upin[kt][G] = Ul[(kt * 64 + ntf[G]) * 64];

  bf16x8 wpin[4][4];                         // W kt0..3
#pragma unroll
  for (int G = 0; G < 4; ++G)
#pragma unroll
    for (int kt = 0; kt < 4; ++kt) wpin[G][kt] = Wl[(kt * 64 + ntf[G]) * 64];

  float bfr[4];
#pragma unroll
  for (int G = 0; G < 4; ++G) bfr[G] = benc[ntf[G] * 16 + l15];

  float c4[4];
  unsigned short hreg[4];
  bf16x8 hfr[8];
#pragma unroll
  for (int q = 0; q < 4; ++q) { c4[q] = 0.f; hreg[q] = 0; }
  H8 z_; z_.u[0] = 0; z_.u[1] = 0;
#pragma unroll
  for (int kt = 0; kt < 8; ++kt) hfr[kt] = z_.v;

  const float* xbase = x + (size_t)(b0 + l15) * 1024 * 128 + lkg * 8;
  const int kt_own = 2 * s + (w >> 1);       // own hstage slice for transpose
  const int lbase = (w & 1) * 32 + (l15 >> 3) * 16 + lkg * 4;
  const int jst = l15 & 7;
  int a = 0;                                  // active-step counter
  bool xvalid = false;
  float4 xa[4][2];

  __syncthreads();

  for (int t = 0; t < 1024; ++t) {
    const unsigned int flag_t = flagp[t];
    if (flag_t == 0u) { xvalid = false; continue; }   // uniform skip

    if (!xvalid) {
      const float* xp = xbase + (size_t)t * 128;
#pragma unroll
      for (int kt = 0; kt < 4; ++kt) {
        xa[kt][0] = *(const float4*)(xp + kt * 32);
        xa[kt][1] = *(const float4*)(xp + kt * 32 + 4);
      }
    }

    f32x4 acc[4];
#pragma unroll
    for (int G = 0; G < 4; ++G) acc[G] = (f32x4){bfr[G], bfr[G], bfr[G], bfr[G]};

    FragU xf[4];
#pragma unroll
    for (int kt = 0; kt < 4; ++kt) {
      xf[kt].us[0] = f2bf(xa[kt][0].x); xf[kt].us[1] = f2bf(xa[kt][0].y);
      xf[kt].us[2] = f2bf(xa[kt][0].z); xf[kt].us[3] = f2bf(xa[kt][0].w);
      xf[kt].us[4] = f2bf(xa[kt][1].x); xf[kt].us[5] = f2bf(xa[kt][1].y);
      xf[kt].us[6] = f2bf(xa[kt][1].z); xf[kt].us[7] = f2bf(xa[kt][1].w);
    }
#pragma unroll
    for (int kt = 0; kt < 4; ++kt)
#pragma unroll
      for (int G = 0; G < 4; ++G) acc[G] = mfma16(xf[kt].v, wpin[G][kt], acc[G]);

#pragma unroll
    for (int kt = 0; kt < 8; ++kt)
#pragma unroll
      for (int G = 0; G < 4; ++G) acc[G] = mfma16(hfr[kt], upin[kt][G], acc[G]);

    // gates (in-register; masked rows carry h,c)
    unsigned short hv[4];
#pragma unroll
    for (int q = 0; q < 4; ++q) {
      float iv = sigf(acc[0][q]);
      float fv = sigf(acc[1][q]);
      float gv = fmaxf(acc[2][q], 0.f);
      float ov = sigf(acc[3][q]);
      float cn = fv * c4[q] + iv * gv;
      float hn = ov * fmaxf(cn, 0.f);
      bool m = (flag_t >> (lkg * 4 + q)) & 1u;
      c4[q] = m ? cn : c4[q];
      unsigned short hh = m ? f2bf(hn) : hreg[q];
      hreg[q] = hh;
      hv[q] = hh;
    }

    __syncthreads();                          // b1: prior hstage reads done
#pragma unroll
    for (int q = 0; q < 4; ++q) hstage[kt_own][lbase + q][jst] = hv[q];
    __syncthreads();                          // b2: transpose complete

    STORE_OWN(hxE);

    if (t < 1023) {                           // prefetch x[t+1] (poll window)
      const float* xq = xbase + (size_t)(t + 1) * 128;
#pragma unroll
      for (int kt = 0; kt < 4; ++kt) {
        xa[kt][0] = *(const float4*)(xq + kt * 32);
        xa[kt][1] = *(const float4*)(xq + kt * 32 + 4);
      }
      xvalid = true;
    } else xvalid = false;

    POLL_REMOTE(hxE);
    __syncthreads();                          // b3: hstage fully populated

#pragma unroll
    for (int kt = 0; kt < 8; ++kt)
      hfr[kt] = *(const bf16x8*)&hstage[kt][lane][0];
    ++a;
  }

  if (w < 2) {                                // own h_fin kt slices
    int kt = 2 * s + w;
    H8 hh_; hh_.v = hfr[kt];
    *(uint4v*)&hfin[((size_t)g * 8 + kt) * 512 + lane * 8] = hh_.q;
  }
}

// =========================== decoder ======================================
__global__ __launch_bounds__(256) __attribute__((amdgpu_waves_per_eu(1, 1)))
void dec_rnn(const float* __restrict__ x,
             const unsigned short* __restrict__ Wd0f,
             const unsigned short* __restrict__ WdLf,
             const unsigned short* __restrict__ Udf,
             const float* __restrict__ bdec,
             const unsigned short* __restrict__ Wof,
             const float* __restrict__ bout,
             const unsigned short* __restrict__ hfin,
             ull* __restrict__ hxD,
             float* __restrict__ out) {
  __shared__ __align__(16) unsigned short hstage[8][64][8];   // 8KB

  const int tid = threadIdx.x;
  const int w = tid >> 6, lane = tid & 63;
  const int l15 = lane & 15, lkg = lane >> 4;
  const int bid = blockIdx.x;
  const int s = bid >> 4, g = bid & 15;
  const int b0 = g * 16;
  int ntf[4];
#pragma unroll
  for (int G = 0; G < 4; ++G) ntf[G] = G * 16 + s * 4 + w;

  const bf16x8* W0l = (const bf16x8*)Wd0f + lane;
  const bf16x8* WLl = (const bf16x8*)WdLf + lane;
  const bf16x8* Ul  = (const bf16x8*)Udf + lane;

  bf16x8 upin[8][4];                          // full U slice in registers
#pragma unroll
  for (int kt = 0; kt < 8; ++kt)
#pragma unroll
    for (int G = 0; G < 4; ++G) upin[kt][G] = Ul[(kt * 64 + ntf[G]) * 64];

  bf16x8 w0pin[4][2];
#pragma unroll
  for (int G = 0; G < 4; ++G)
#pragma unroll
    for (int kt = 0; kt < 2; ++kt) w0pin[G][kt] = W0l[(kt * 64 + ntf[G]) * 64];

  f32x4 lat[4];                               // b_dec + h_fin @ W_dec[64:]
  {
    bf16x8 ha[8];
#pragma unroll
    for (int kt = 0; kt < 8; ++kt)
      ha[kt] = *(const bf16x8*)&hfin[((size_t)g * 8 + kt) * 512 + lane * 8];
#pragma unroll
    for (int G = 0; G < 4; ++G) {
      float bd = bdec[ntf[G] * 16 + l15];
      lat[G] = (f32x4){bd, bd, bd, bd};
    }
#pragma unroll
    for (int kt = 0; kt < 8; ++kt)
#pragma unroll
      for (int G = 0; G < 4; ++G)
        lat[G] = mfma16(ha[kt], WLl[(kt * 64 + ntf[G]) * 64], lat[G]);
  }

  bf16x8 wofr[8];                             // W_out cols s*16.. (wave 0)
  if (w == 0) {
#pragma unroll
    for (int kt = 0; kt < 8; ++kt)
      wofr[kt] = ((const bf16x8*)Wof)[(kt * 4 + s) * 64 + lane];
  }
  const float bo = bout[s * 16 + l15];

  float c4[4];
  bf16x8 hfr[8];
#pragma unroll
  for (int q = 0; q < 4; ++q) c4[q] = 0.f;
  H8 z_; z_.u[0] = 0; z_.u[1] = 0;
#pragma unroll
  for (int kt = 0; kt < 8; ++kt) hfr[kt] = z_.v;

  const float* xbase = x + (size_t)(b0 + l15) * 1024 * 128 + lkg * 8;
  const int kt_own = 2 * s + (w >> 1);
  const int lbase = (w & 1) * 32 + (l15 >> 3) * 16 + lkg * 4;
  const int jst = l15 & 7;

  float4 xa[2][2];
  xa[0][0] = *(const float4*)(xbase);      xa[0][1] = *(const float4*)(xbase + 4);
  xa[1][0] = *(const float4*)(xbase + 32); xa[1][1] = *(const float4*)(xbase + 36);

  __syncthreads();

  for (int t = 0; t < 1024; ++t) {
    const int a = t;
    f32x4 acc[4];
#pragma unroll
    for (int G = 0; G < 4; ++G) acc[G] = lat[G];

    FragU xf[2];
#pragma unroll
    for (int kt = 0; kt < 2; ++kt) {
      xf[kt].us[0] = f2bf(xa[kt][0].x); xf[kt].us[1] = f2bf(xa[kt][0].y);
      xf[kt].us[2] = f2bf(xa[kt][0].z); xf[kt].us[3] = f2bf(xa[kt][0].w);
      xf[kt].us[4] = f2bf(xa[kt][1].x); xf[kt].us[5] = f2bf(xa[kt][1].y);
      xf[kt].us[6] = f2bf(xa[kt][1].z); xf[kt].us[7] = f2bf(xa[kt][1].w);
    }
#pragma unroll
    for (int kt = 0; kt < 2; ++kt)
#pragma unroll
      for (int G = 0; G < 4; ++G) acc[G] = mfma16(xf[kt].v, w0pin[G][kt], acc[G]);

#pragma unroll
    for (int kt = 0; kt < 8; ++kt)
#pragma unroll
      for (int G = 0; G < 4; ++G) acc[G] = mfma16(hfr[kt], upin[kt][G], acc[G]);

    unsigned short hv[4];
#pragma unroll
    for (int q = 0; q < 4; ++q) {
      float iv = sigf(acc[0][q]);
      float fv = sigf(acc[1][q]);
      float gv = fmaxf(acc[2][q], 0.f);
      float ov = sigf(acc[3][q]);
      float cn = fv * c4[q] + iv * gv;
      float hn = ov * fmaxf(cn, 0.f);
      c4[q] = cn;
      hv[q] = f2bf(hn);
    }

    __syncthreads();                          // b1
#pragma unroll
    for (int q = 0; q < 4; ++q) hstage[kt_own][lbase + q][jst] = hv[q];
    __syncthreads();                          // b2

    STORE_OWN(hxD);

    // poll-window work: out-proj(t-1) on wave 0 (hfr = h_{t-1}); x prefetch
    if (t > 0 && w == 0) {
      f32x4 oa = {bo, bo, bo, bo};
#pragma unroll
      for (int kt = 0; kt < 8; ++kt) oa = mfma16(hfr[kt], wofr[kt], oa);
#pragma unroll
      for (int q = 0; q < 4; ++q)
        out[((size_t)(b0 + lkg * 4 + q) * 1024 + (t - 1)) * 64 + s * 16 + l15] = oa[q];
    }
    if (t < 1023) {
      const float* xq = xbase + (size_t)(t + 1) * 128;
      xa[0][0] = *(const float4*)(xq);      xa[0][1] = *(const float4*)(xq + 4);
      xa[1][0] = *(const float4*)(xq + 32); xa[1][1] = *(const float4*)(xq + 36);
    }

    POLL_REMOTE(hxD);
    __syncthreads();                          // b3

#pragma unroll
    for (int kt = 0; kt < 8; ++kt)
      hfr[kt] = *(const bf16x8*)&hstage[kt][lane][0];
  }

  if (w == 0) {                               // final out-proj (t=1023)
    f32x4 oa = {bo, bo, bo, bo};
#pragma unroll
    for (int kt = 0; kt < 8; ++kt) oa = mfma16(hfr[kt], wofr[kt], oa);
#pragma unroll
    for (int q = 0; q < 4; ++q)
      out[((size_t)(b0 + lkg * 4 + q) * 1024 + 1023) * 64 + s * 16 + l15] = oa[q];
  }
}

extern "C" void kernel_launch(void* const* d_in, const int* in_sizes, int n_in,
                              void* d_out, int out_size, void* d_ws, size_t ws_size,
                              hipStream_t stream) {
  const float* inputs = (const float*)d_in[0];
  const float* W_enc  = (const float*)d_in[1];
  const float* U_enc  = (const float*)d_in[2];
  const float* b_enc  = (const float*)d_in[3];
  const float* W_dec  = (const float*)d_in[4];
  const float* U_dec  = (const float*)d_in[5];
  const float* b_dec  = (const float*)d_in[6];
  const float* W_out  = (const float*)d_in[7];
  const float* b_out  = (const float*)d_in[8];

  char* ws = (char*)d_ws;
  unsigned short* Uef   = (unsigned short*)(ws + 0);        // 512K
  unsigned short* Udf   = (unsigned short*)(ws + 524288);   // 512K
  unsigned short* Wef   = (unsigned short*)(ws + 1048576);  // 256K
  unsigned short* Wd0f  = (unsigned short*)(ws + 1310720);  // 128K
  unsigned short* WdLf  = (unsigned short*)(ws + 1441792);  // 512K
  unsigned short* Wof   = (unsigned short*)(ws + 1966080);  // 32K
  unsigned short* hfin  = (unsigned short*)(ws + 1998848);  // 128K
  unsigned int*   fmask = (unsigned int*)(ws + 2129920);    // 64K
  ull*            hxE   = (ull*)(ws + 2195456);             // 384K tagged
  ull*            hxD   = (ull*)(ws + 2588672);             // 384K tagged

  mask_flags<<<1024, 256, 0, stream>>>(inputs, fmask);
  pack_frags<<<128, 256, 0, stream>>>(U_enc, Uef, 256, 1024);
  pack_frags<<<128, 256, 0, stream>>>(U_dec, Udf, 256, 1024);
  pack_frags<<<128, 256, 0, stream>>>(W_enc, Wef, 128, 1024);
  pack_frags<<<128, 256, 0, stream>>>(W_dec, Wd0f, 64, 1024);
  pack_frags<<<128, 256, 0, stream>>>(W_dec + 64 * 1024, WdLf, 256, 1024);
  pack_frags<<<32, 256, 0, stream>>>(W_out, Wof, 256, 64);

  enc_rnn<<<64, 256, 0, stream>>>(inputs, Wef, Uef, b_enc, fmask, hxE, hfin);
  dec_rnn<<<64, 256, 0, stream>>>(inputs, Wd0f, WdLf, Udf, b_dec, Wof, b_out,
                                  hfin, hxD, (float*)d_out);
}